// Round 5
// baseline (412.524 us; speedup 1.0000x reference)
//
#include <hip/hip_runtime.h>

#define T_TOK 4096
#define D_DIM 1024
#define F_DIM 2048
#define E_NUM 8
#define MAX_TILES 72

typedef __attribute__((ext_vector_type(8))) short bf16x8;
typedef __attribute__((ext_vector_type(4))) float f32x4;

__device__ __forceinline__ unsigned short f2bf(float f) {
  unsigned u = __builtin_bit_cast(unsigned, f);
  unsigned r = 0x7FFFu + ((u >> 16) & 1u);
  return (unsigned short)((u + r) >> 16);
}

__device__ __forceinline__ void gload16(const unsigned short* g, unsigned short* l) {
  __builtin_amdgcn_global_load_lds(
      (const __attribute__((address_space(1))) unsigned int*)g,
      (__attribute__((address_space(3))) unsigned int*)l, 16, 0, 0);
}

__device__ __forceinline__ f32x4 mfma16(bf16x8 a, bf16x8 b, f32x4 c) {
  return __builtin_amdgcn_mfma_f32_16x16x32_bf16(a, b, c, 0, 0, 0);
}

// ---------------- transpose + convert: src [M][N] fp32 -> dst [N][M] bf16 ----------------
__global__ __launch_bounds__(256) void transpose_cvt_kernel(const float* __restrict__ src,
                                                            unsigned short* __restrict__ dst,
                                                            int M, int N) {
  __shared__ float tile[64][65];
  size_t eo = (size_t)blockIdx.z * (size_t)M * (size_t)N;
  src += eo; dst += eo;
  int i0 = blockIdx.y * 64, j0 = blockIdx.x * 64;
  int tid = threadIdx.x;
  int lr = tid >> 4;           // 0..15
  int lc = (tid & 15) * 4;     // 0..60
  #pragma unroll
  for (int p = 0; p < 4; p++) {
    int row = p * 16 + lr;
    float4 v = *(const float4*)&src[(size_t)(i0 + row) * N + j0 + lc];
    tile[row][lc + 0] = v.x; tile[row][lc + 1] = v.y;
    tile[row][lc + 2] = v.z; tile[row][lc + 3] = v.w;
  }
  __syncthreads();
  #pragma unroll
  for (int p = 0; p < 4; p++) {
    int orow = p * 16 + lr;    // N-dim index
    unsigned short b0 = f2bf(tile[lc + 0][orow]);
    unsigned short b1 = f2bf(tile[lc + 1][orow]);
    unsigned short b2 = f2bf(tile[lc + 2][orow]);
    unsigned short b3 = f2bf(tile[lc + 3][orow]);
    uint2 o;
    o.x = b0 | ((unsigned)b1 << 16);
    o.y = b2 | ((unsigned)b3 << 16);
    *(uint2*)&dst[(size_t)(j0 + orow) * M + i0 + lc] = o;
  }
}

// ---------------- router (+ fused x->bf16 convert): 1 wave per token ----------------
__global__ __launch_bounds__(256) void router_kernel(const float* __restrict__ x,
                                                     const float* __restrict__ gw,
                                                     int* __restrict__ counts,
                                                     int* __restrict__ list,
                                                     float* __restrict__ wts,
                                                     unsigned short* __restrict__ Xb) {
  int lane = threadIdx.x & 63;
  int t = blockIdx.x * 4 + (threadIdx.x >> 6);
  float acc[E_NUM];
  #pragma unroll
  for (int e = 0; e < E_NUM; e++) acc[e] = 0.f;
  const float* xr = x + (size_t)t * D_DIM;
  unsigned short* xbr = Xb + (size_t)t * D_DIM;
  #pragma unroll
  for (int j = 0; j < D_DIM / 64; j++) {
    int d = lane + 64 * j;
    float xv = xr[d];
    xbr[d] = f2bf(xv);
    const float4* g = reinterpret_cast<const float4*>(gw + (size_t)d * E_NUM);
    float4 g0 = g[0], g1 = g[1];
    acc[0] += xv * g0.x; acc[1] += xv * g0.y; acc[2] += xv * g0.z; acc[3] += xv * g0.w;
    acc[4] += xv * g1.x; acc[5] += xv * g1.y; acc[6] += xv * g1.z; acc[7] += xv * g1.w;
  }
  #pragma unroll
  for (int e = 0; e < E_NUM; e++) {
    #pragma unroll
    for (int off = 32; off > 0; off >>= 1) acc[e] += __shfl_xor(acc[e], off);
  }
  if (lane == 0) {
    int e1 = 0; float l1 = acc[0];
    #pragma unroll
    for (int e = 1; e < E_NUM; e++) { if (acc[e] > l1) { l1 = acc[e]; e1 = e; } }
    int e2 = -1; float l2 = -1e30f;
    #pragma unroll
    for (int e = 0; e < E_NUM; e++) { if (e != e1 && acc[e] > l2) { l2 = acc[e]; e2 = e; } }
    float wa = 1.f / (1.f + expf(l2 - l1));
    float wb = 1.f / (1.f + expf(l1 - l2));
    int p1 = atomicAdd(&counts[e1], 1);
    list[e1 * T_TOK + p1] = t * 2;     wts[e1 * T_TOK + p1] = wa;
    int p2 = atomicAdd(&counts[e2], 1);
    list[e2 * T_TOK + p2] = t * 2 + 1; wts[e2 * T_TOK + p2] = wb;
  }
}

// ---------------- tile descriptors: (expert, base, cnt), sentinel e=-1 ----------------
__global__ void tiles_kernel(const int* __restrict__ counts, int4* __restrict__ tiles) {
  if (threadIdx.x == 0) {
    int n = 0;
    for (int e = 0; e < E_NUM; e++) {
      int cnt = counts[e];
      for (int b = 0; b < cnt; b += 128) {
        int4 t; t.x = e; t.y = b; t.z = cnt; t.w = 0;
        tiles[n++] = t;
      }
    }
    for (; n < MAX_TILES; n++) {
      int4 t; t.x = -1; t.y = 0; t.z = 0; t.w = 0;
      tiles[n] = t;
    }
  }
}

// ---------------- GEMM1: H = silu(X@w1) * (X@w3), 128x64 dual tile, 2-phase dbuf ----------
__global__ __launch_bounds__(256) void gemm1_kernel(
    const unsigned short* __restrict__ Xb,   // [T][D] bf16
    const unsigned short* __restrict__ W1t,  // [E][F][D] bf16
    const unsigned short* __restrict__ W3t,  // [E][F][D] bf16
    const int4* __restrict__ tiles, const int* __restrict__ list,
    unsigned short* __restrict__ H) {        // [T*2][F] bf16
  __shared__ unsigned short As[2][128 * 64];   // 32 KB
  __shared__ unsigned short B1s[2][64 * 64];   // 16 KB
  __shared__ unsigned short B3s[2][64 * 64];   // 16 KB
  __shared__ int rid_s[128];

  int4 td = tiles[blockIdx.y];
  int e = td.x;
  if (e < 0) return;
  int base = td.y, cnt = td.z;
  int nt = blockIdx.x;          // 0..31 over F/64
  int tid = threadIdx.x;

  if (tid < 128) {
    int r = base + tid; if (r > cnt - 1) r = cnt - 1;
    rid_s[tid] = list[e * T_TOK + r];
  }
  __syncthreads();

  int lane = tid & 63, wid = tid >> 6;
  int sr = lane >> 3;                      // 0..7 row within 8-row group
  int sg = (lane & 7) ^ (sr & 7);          // pre-swizzled source granule
  const unsigned short* a_src[4];
  #pragma unroll
  for (int t = 0; t < 4; t++)
    a_src[t] = Xb + (size_t)(rid_s[(wid << 5) + t * 8 + sr] >> 1) * D_DIM + sg * 8;
  const unsigned short* b1_src =
      W1t + ((size_t)e * F_DIM + nt * 64 + (wid << 4) + sr) * D_DIM + sg * 8;
  const unsigned short* b3_src =
      W3t + ((size_t)e * F_DIM + nt * 64 + (wid << 4) + sr) * D_DIM + sg * 8;

  int wm = (wid >> 1) * 64, wn = (wid & 1) * 32;
  int frow = lane & 15;
  int fk = lane >> 4;

  f32x4 acc1[4][2], acc3[4][2];
  #pragma unroll
  for (int mf = 0; mf < 4; mf++)
    #pragma unroll
    for (int nf = 0; nf < 2; nf++) {
      f32x4 z = {0.f, 0.f, 0.f, 0.f};
      acc1[mf][nf] = z; acc3[mf][nf] = z;
    }

  auto stage = [&](int b, int k0) {
    #pragma unroll
    for (int t = 0; t < 4; t++)
      gload16(a_src[t] + k0, &As[b][((wid << 5) + t * 8) * 64]);
    #pragma unroll
    for (int t = 0; t < 2; t++) {
      gload16(b1_src + (size_t)(t * 8) * D_DIM + k0, &B1s[b][((wid << 4) + t * 8) * 64]);
      gload16(b3_src + (size_t)(t * 8) * D_DIM + k0, &B3s[b][((wid << 4) + t * 8) * 64]);
    }
  };
  auto compute = [&](int b) {
    #pragma unroll
    for (int kc = 0; kc < 2; kc++) {
      int gk = kc * 4 + fk;
      bf16x8 a[4], b1[2], b3[2];
      #pragma unroll
      for (int mf = 0; mf < 4; mf++) {
        int m = wm + mf * 16 + frow;
        a[mf] = *(const bf16x8*)&As[b][m * 64 + ((gk ^ (m & 7)) * 8)];
      }
      #pragma unroll
      for (int nf = 0; nf < 2; nf++) {
        int n = wn + nf * 16 + frow;
        b1[nf] = *(const bf16x8*)&B1s[b][n * 64 + ((gk ^ (n & 7)) * 8)];
        b3[nf] = *(const bf16x8*)&B3s[b][n * 64 + ((gk ^ (n & 7)) * 8)];
      }
      #pragma unroll
      for (int mf = 0; mf < 4; mf++)
        #pragma unroll
        for (int nf = 0; nf < 2; nf++) {
          acc1[mf][nf] = mfma16(a[mf], b1[nf], acc1[mf][nf]);
          acc3[mf][nf] = mfma16(a[mf], b3[nf], acc3[mf][nf]);
        }
    }
  };

  int cur = 0;
  stage(0, 0);
  __syncthreads();
  for (int k0 = 64; k0 < D_DIM; k0 += 64) {
    stage(cur ^ 1, k0);     // issue next-tile loads (latency hides under compute)
    compute(cur);
    __syncthreads();        // drains vmcnt+lgkmcnt, next buffer ready
    cur ^= 1;
  }
  compute(cur);

  #pragma unroll
  for (int mf = 0; mf < 4; mf++) {
    #pragma unroll
    for (int i = 0; i < 4; i++) {
      int m = wm + mf * 16 + fk * 4 + i;
      if (base + m < cnt) {
        int rid = rid_s[m];
        unsigned short* hrow = H + (size_t)rid * F_DIM + nt * 64 + wn;
        #pragma unroll
        for (int nf = 0; nf < 2; nf++) {
          float z = acc1[mf][nf][i];
          float u = acc3[mf][nf][i];
          hrow[nf * 16 + frow] = f2bf((z / (1.f + expf(-z))) * u);
        }
      }
    }
  }
}

// ---------------- GEMM2: out += (H @ w2) * combine_weight, 128x128 tile, 2-phase dbuf ------
__global__ __launch_bounds__(256) void gemm2_kernel(
    const unsigned short* __restrict__ H,    // [T*2][F] bf16
    const unsigned short* __restrict__ W2t,  // [E][D][F] bf16
    const int4* __restrict__ tiles, const int* __restrict__ list,
    const float* __restrict__ wts,
    float* __restrict__ out) {               // [T][D] fp32 (pre-zeroed)
  __shared__ unsigned short As[2][128 * 64];
  __shared__ unsigned short Bs[2][128 * 64];
  __shared__ int rid_s[128];
  __shared__ float wt_s[128];

  int4 td = tiles[blockIdx.y];
  int e = td.x;
  if (e < 0) return;
  int base = td.y, cnt = td.z;
  int nt = blockIdx.x;   // 0..7 over D/128
  int tid = threadIdx.x;

  if (tid < 128) {
    int r = base + tid; if (r > cnt - 1) r = cnt - 1;
    rid_s[tid] = list[e * T_TOK + r];
    wt_s[tid] = wts[e * T_TOK + r];
  }
  __syncthreads();

  int lane = tid & 63, wid = tid >> 6;
  int srow = (wid << 5) + (lane >> 3);
  int sg = (lane & 7) ^ ((lane >> 3) & 7);
  const unsigned short* a_src[4];
  #pragma unroll
  for (int t = 0; t < 4; t++)
    a_src[t] = H + (size_t)rid_s[srow + t * 8] * F_DIM + sg * 8;
  const unsigned short* b_src =
      W2t + ((size_t)e * D_DIM + nt * 128 + srow) * F_DIM + sg * 8;

  int wm = (wid >> 1) * 64, wn = (wid & 1) * 64;
  int frow = lane & 15;
  int fk = lane >> 4;

  f32x4 acc[4][4];
  #pragma unroll
  for (int mf = 0; mf < 4; mf++)
    #pragma unroll
    for (int nf = 0; nf < 4; nf++) {
      f32x4 z = {0.f, 0.f, 0.f, 0.f};
      acc[mf][nf] = z;
    }

  auto stage = [&](int b, int k0) {
    #pragma unroll
    for (int t = 0; t < 4; t++) {
      int lrow = (wid << 5) + (t << 3);
      gload16(a_src[t] + k0, &As[b][lrow * 64]);
      gload16(b_src + (size_t)(t * 8) * F_DIM + k0, &Bs[b][lrow * 64]);
    }
  };
  auto compute = [&](int bb) {
    #pragma unroll
    for (int kc = 0; kc < 2; kc++) {
      int gk = kc * 4 + fk;
      bf16x8 a[4], b[4];
      #pragma unroll
      for (int mf = 0; mf < 4; mf++) {
        int m = wm + mf * 16 + frow;
        a[mf] = *(const bf16x8*)&As[bb][m * 64 + ((gk ^ (m & 7)) * 8)];
      }
      #pragma unroll
      for (int nf = 0; nf < 4; nf++) {
        int n = wn + nf * 16 + frow;
        b[nf] = *(const bf16x8*)&Bs[bb][n * 64 + ((gk ^ (n & 7)) * 8)];
      }
      #pragma unroll
      for (int mf = 0; mf < 4; mf++)
        #pragma unroll
        for (int nf = 0; nf < 4; nf++)
          acc[mf][nf] = mfma16(a[mf], b[nf], acc[mf][nf]);
    }
  };

  int cur = 0;
  stage(0, 0);
  __syncthreads();
  for (int k0 = 64; k0 < F_DIM; k0 += 64) {
    stage(cur ^ 1, k0);
    compute(cur);
    __syncthreads();
    cur ^= 1;
  }
  compute(cur);

  #pragma unroll
  for (int mf = 0; mf < 4; mf++) {
    #pragma unroll
    for (int i = 0; i < 4; i++) {
      int m = wm + mf * 16 + fk * 4 + i;
      if (base + m < cnt) {
        int tok = rid_s[m] >> 1;
        float w = wt_s[m];
        float* orow = out + (size_t)tok * D_DIM + nt * 128 + wn;
        #pragma unroll
        for (int nf = 0; nf < 4; nf++)
          atomicAdd(&orow[nf * 16 + frow], acc[mf][nf][i] * w);
      }
    }
  }
}

extern "C" void kernel_launch(void* const* d_in, const int* in_sizes, int n_in,
                              void* d_out, int out_size, void* d_ws, size_t ws_size,
                              hipStream_t stream) {
  const float* x  = (const float*)d_in[0];
  const float* gw = (const float*)d_in[1];
  const float* w1 = (const float*)d_in[2];
  const float* w2 = (const float*)d_in[3];
  const float* w3 = (const float*)d_in[4];
  float* out = (float*)d_out;

  char* ws = (char*)d_ws;
  const size_t LISTB = (size_t)E_NUM * T_TOK * 4;
  size_t o_counts = 0;
  size_t o_tiles  = 256;
  size_t o_list   = 2048;
  size_t o_wts    = o_list + LISTB;
  size_t o_Xb     = o_wts + LISTB;
  size_t o_W1t    = o_Xb + (size_t)T_TOK * D_DIM * 2;
  size_t wt_sz    = (size_t)E_NUM * F_DIM * D_DIM * 2;
  size_t o_W3t    = o_W1t + wt_sz;
  size_t o_W2t    = o_W3t + wt_sz;
  size_t o_H      = o_W2t + wt_sz;

  int* counts = (int*)(ws + o_counts);
  int4* tiles = (int4*)(ws + o_tiles);
  int* list   = (int*)(ws + o_list);
  float* wts  = (float*)(ws + o_wts);
  unsigned short* Xb  = (unsigned short*)(ws + o_Xb);
  unsigned short* W1t = (unsigned short*)(ws + o_W1t);
  unsigned short* W3t = (unsigned short*)(ws + o_W3t);
  unsigned short* W2t = (unsigned short*)(ws + o_W2t);
  unsigned short* H   = (unsigned short*)(ws + o_H);

  hipMemsetAsync(counts, 0, 256, stream);
  hipMemsetAsync(out, 0, (size_t)out_size * 4, stream);

  transpose_cvt_kernel<<<dim3(F_DIM / 64, D_DIM / 64, E_NUM), 256, 0, stream>>>(w1, W1t, D_DIM, F_DIM);
  transpose_cvt_kernel<<<dim3(F_DIM / 64, D_DIM / 64, E_NUM), 256, 0, stream>>>(w3, W3t, D_DIM, F_DIM);
  transpose_cvt_kernel<<<dim3(D_DIM / 64, F_DIM / 64, E_NUM), 256, 0, stream>>>(w2, W2t, F_DIM, D_DIM);

  router_kernel<<<dim3(T_TOK / 4), 256, 0, stream>>>(x, gw, counts, list, wts, Xb);
  tiles_kernel<<<dim3(1), 64, 0, stream>>>(counts, tiles);

  gemm1_kernel<<<dim3(F_DIM / 64, MAX_TILES), 256, 0, stream>>>(
      Xb, W1t, W3t, tiles, list, H);
  gemm2_kernel<<<dim3(D_DIM / 128, MAX_TILES), 256, 0, stream>>>(
      H, W2t, tiles, list, wts, out);
}

// Round 6
// 349.697 us; speedup vs baseline: 1.1797x; 1.1797x over previous
//
#include <hip/hip_runtime.h>

#define T_TOK 4096
#define D_DIM 1024
#define F_DIM 2048
#define E_NUM 8
#define MAX_TILES 72

typedef __attribute__((ext_vector_type(8))) short bf16x8;
typedef __attribute__((ext_vector_type(4))) float f32x4;

__device__ __forceinline__ unsigned short f2bf(float f) {
  unsigned u = __builtin_bit_cast(unsigned, f);
  unsigned r = 0x7FFFu + ((u >> 16) & 1u);
  return (unsigned short)((u + r) >> 16);
}

__device__ __forceinline__ void gload16(const unsigned short* g, unsigned short* l) {
  __builtin_amdgcn_global_load_lds(
      (const __attribute__((address_space(1))) unsigned int*)g,
      (__attribute__((address_space(3))) unsigned int*)l, 16, 0, 0);
}

__device__ __forceinline__ f32x4 mfma16(bf16x8 a, bf16x8 b, f32x4 c) {
  return __builtin_amdgcn_mfma_f32_16x16x32_bf16(a, b, c, 0, 0, 0);
}

// ---------------- transpose + convert: src [M][N] fp32 -> dst [N][M] bf16 ----------------
__global__ __launch_bounds__(256) void transpose_cvt_kernel(const float* __restrict__ src,
                                                            unsigned short* __restrict__ dst,
                                                            int M, int N) {
  __shared__ float tile[64][65];
  size_t eo = (size_t)blockIdx.z * (size_t)M * (size_t)N;
  src += eo; dst += eo;
  int i0 = blockIdx.y * 64, j0 = blockIdx.x * 64;
  int tid = threadIdx.x;
  int lr = tid >> 4;           // 0..15
  int lc = (tid & 15) * 4;     // 0..60
  #pragma unroll
  for (int p = 0; p < 4; p++) {
    int row = p * 16 + lr;
    float4 v = *(const float4*)&src[(size_t)(i0 + row) * N + j0 + lc];
    tile[row][lc + 0] = v.x; tile[row][lc + 1] = v.y;
    tile[row][lc + 2] = v.z; tile[row][lc + 3] = v.w;
  }
  __syncthreads();
  #pragma unroll
  for (int p = 0; p < 4; p++) {
    int orow = p * 16 + lr;    // N-dim index
    unsigned short b0 = f2bf(tile[lc + 0][orow]);
    unsigned short b1 = f2bf(tile[lc + 1][orow]);
    unsigned short b2 = f2bf(tile[lc + 2][orow]);
    unsigned short b3 = f2bf(tile[lc + 3][orow]);
    uint2 o;
    o.x = b0 | ((unsigned)b1 << 16);
    o.y = b2 | ((unsigned)b3 << 16);
    *(uint2*)&dst[(size_t)(j0 + orow) * M + i0 + lc] = o;
  }
}

// ---------------- router (+ fused x->bf16 convert): 1 wave per token ----------------
__global__ __launch_bounds__(256) void router_kernel(const float* __restrict__ x,
                                                     const float* __restrict__ gw,
                                                     int* __restrict__ counts,
                                                     int* __restrict__ list,
                                                     float* __restrict__ wts,
                                                     unsigned short* __restrict__ Xb) {
  int lane = threadIdx.x & 63;
  int t = blockIdx.x * 4 + (threadIdx.x >> 6);
  float acc[E_NUM];
  #pragma unroll
  for (int e = 0; e < E_NUM; e++) acc[e] = 0.f;
  const float* xr = x + (size_t)t * D_DIM;
  unsigned short* xbr = Xb + (size_t)t * D_DIM;
  #pragma unroll
  for (int j = 0; j < D_DIM / 64; j++) {
    int d = lane + 64 * j;
    float xv = xr[d];
    xbr[d] = f2bf(xv);
    const float4* g = reinterpret_cast<const float4*>(gw + (size_t)d * E_NUM);
    float4 g0 = g[0], g1 = g[1];
    acc[0] += xv * g0.x; acc[1] += xv * g0.y; acc[2] += xv * g0.z; acc[3] += xv * g0.w;
    acc[4] += xv * g1.x; acc[5] += xv * g1.y; acc[6] += xv * g1.z; acc[7] += xv * g1.w;
  }
  #pragma unroll
  for (int e = 0; e < E_NUM; e++) {
    #pragma unroll
    for (int off = 32; off > 0; off >>= 1) acc[e] += __shfl_xor(acc[e], off);
  }
  if (lane == 0) {
    int e1 = 0; float l1 = acc[0];
    #pragma unroll
    for (int e = 1; e < E_NUM; e++) { if (acc[e] > l1) { l1 = acc[e]; e1 = e; } }
    int e2 = -1; float l2 = -1e30f;
    #pragma unroll
    for (int e = 0; e < E_NUM; e++) { if (e != e1 && acc[e] > l2) { l2 = acc[e]; e2 = e; } }
    float wa = 1.f / (1.f + expf(l2 - l1));
    float wb = 1.f / (1.f + expf(l1 - l2));
    int p1 = atomicAdd(&counts[e1], 1);
    list[e1 * T_TOK + p1] = t * 2;     wts[e1 * T_TOK + p1] = wa;
    int p2 = atomicAdd(&counts[e2], 1);
    list[e2 * T_TOK + p2] = t * 2 + 1; wts[e2 * T_TOK + p2] = wb;
  }
}

// ---------------- tile descriptors: (expert, base, cnt), sentinel e=-1 ----------------
__global__ void tiles_kernel(const int* __restrict__ counts, int4* __restrict__ tiles) {
  if (threadIdx.x == 0) {
    int n = 0;
    for (int e = 0; e < E_NUM; e++) {
      int cnt = counts[e];
      for (int b = 0; b < cnt; b += 128) {
        int4 t; t.x = e; t.y = b; t.z = cnt; t.w = 0;
        tiles[n++] = t;
      }
    }
    for (; n < MAX_TILES; n++) {
      int4 t; t.x = -1; t.y = 0; t.z = 0; t.w = 0;
      tiles[n] = t;
    }
  }
}

// ---------------- GEMM1: H = silu(X@w1)*(X@w3), 128x64 dual tile, 8 waves, 32-acc/wave ----
__global__ __launch_bounds__(512, 4) void gemm1_kernel(
    const unsigned short* __restrict__ Xb,   // [T][D] bf16
    const unsigned short* __restrict__ W1t,  // [E][F][D] bf16
    const unsigned short* __restrict__ W3t,  // [E][F][D] bf16
    const int4* __restrict__ tiles, const int* __restrict__ list,
    unsigned short* __restrict__ H) {        // [T*2][F] bf16
  __shared__ unsigned short As[128 * 64];    // 16 KB
  __shared__ unsigned short B1s[64 * 64];    // 8 KB
  __shared__ unsigned short B3s[64 * 64];    // 8 KB
  __shared__ int rid_s[128];

  int4 td = tiles[blockIdx.y];
  int e = td.x;
  if (e < 0) return;
  int base = td.y, cnt = td.z;
  int nt = blockIdx.x;          // 0..31 over F/64
  int tid = threadIdx.x;

  if (tid < 128) {
    int r = base + tid; if (r > cnt - 1) r = cnt - 1;
    rid_s[tid] = list[e * T_TOK + r];
  }
  __syncthreads();

  int lane = tid & 63, wid = tid >> 6;       // wid 0..7
  int sr = lane >> 3;                        // 0..7 row within 8-row group
  int sg = (lane & 7) ^ sr;                  // pre-swizzled source granule
  // staging: each wave: 2 A-insts (rows wid*16..+15), 1 B1-inst + 1 B3-inst (rows wid*8..+7)
  const unsigned short* a_src[2];
  #pragma unroll
  for (int t = 0; t < 2; t++)
    a_src[t] = Xb + (size_t)(rid_s[wid * 16 + t * 8 + sr] >> 1) * D_DIM + sg * 8;
  const unsigned short* b1_src =
      W1t + ((size_t)e * F_DIM + nt * 64 + wid * 8 + sr) * D_DIM + sg * 8;
  const unsigned short* b3_src =
      W3t + ((size_t)e * F_DIM + nt * 64 + wid * 8 + sr) * D_DIM + sg * 8;

  // compute: 4x2 wave grid, wave owns 32 rows x 32 cols of BOTH branches (32 acc regs)
  int wm = (wid >> 1) * 32, wn = (wid & 1) * 32;
  int frow = lane & 15;
  int fk = lane >> 4;

  f32x4 acc1[2][2], acc3[2][2];
  #pragma unroll
  for (int mf = 0; mf < 2; mf++)
    #pragma unroll
    for (int nf = 0; nf < 2; nf++) {
      f32x4 z = {0.f, 0.f, 0.f, 0.f};
      acc1[mf][nf] = z; acc3[mf][nf] = z;
    }

  for (int k0 = 0; k0 < D_DIM; k0 += 64) {
    #pragma unroll
    for (int t = 0; t < 2; t++)
      gload16(a_src[t] + k0, &As[(wid * 16 + t * 8) * 64]);
    gload16(b1_src + k0, &B1s[(wid * 8) * 64]);
    gload16(b3_src + k0, &B3s[(wid * 8) * 64]);
    __syncthreads();
    #pragma unroll
    for (int kc = 0; kc < 2; kc++) {
      int gk = kc * 4 + fk;
      bf16x8 a[2], b1[2], b3[2];
      #pragma unroll
      for (int mf = 0; mf < 2; mf++) {
        int m = wm + mf * 16 + frow;
        a[mf] = *(const bf16x8*)&As[m * 64 + ((gk ^ (m & 7)) * 8)];
      }
      #pragma unroll
      for (int nf = 0; nf < 2; nf++) {
        int n = wn + nf * 16 + frow;
        b1[nf] = *(const bf16x8*)&B1s[n * 64 + ((gk ^ (n & 7)) * 8)];
        b3[nf] = *(const bf16x8*)&B3s[n * 64 + ((gk ^ (n & 7)) * 8)];
      }
      #pragma unroll
      for (int mf = 0; mf < 2; mf++)
        #pragma unroll
        for (int nf = 0; nf < 2; nf++) {
          acc1[mf][nf] = mfma16(a[mf], b1[nf], acc1[mf][nf]);
          acc3[mf][nf] = mfma16(a[mf], b3[nf], acc3[mf][nf]);
        }
    }
    __syncthreads();
  }

  #pragma unroll
  for (int mf = 0; mf < 2; mf++) {
    #pragma unroll
    for (int i = 0; i < 4; i++) {
      int m = wm + mf * 16 + fk * 4 + i;
      if (base + m < cnt) {
        int rid = rid_s[m];
        unsigned short* hrow = H + (size_t)rid * F_DIM + nt * 64 + wn;
        #pragma unroll
        for (int nf = 0; nf < 2; nf++) {
          float z = acc1[mf][nf][i];
          float u = acc3[mf][nf][i];
          hrow[nf * 16 + frow] = f2bf((z / (1.f + expf(-z))) * u);
        }
      }
    }
  }
}

// ---------------- GEMM2: out += (H @ w2) * weight, 128x128, 8 waves, 32-acc/wave ----------
__global__ __launch_bounds__(512, 4) void gemm2_kernel(
    const unsigned short* __restrict__ H,    // [T*2][F] bf16
    const unsigned short* __restrict__ W2t,  // [E][D][F] bf16
    const int4* __restrict__ tiles, const int* __restrict__ list,
    const float* __restrict__ wts,
    float* __restrict__ out) {               // [T][D] fp32 (pre-zeroed)
  __shared__ unsigned short As[128 * 64];    // 16 KB
  __shared__ unsigned short Bs[128 * 64];    // 16 KB
  __shared__ int rid_s[128];
  __shared__ float wt_s[128];

  int4 td = tiles[blockIdx.y];
  int e = td.x;
  if (e < 0) return;
  int base = td.y, cnt = td.z;
  int nt = blockIdx.x;   // 0..7 over D/128
  int tid = threadIdx.x;

  if (tid < 128) {
    int r = base + tid; if (r > cnt - 1) r = cnt - 1;
    rid_s[tid] = list[e * T_TOK + r];
    wt_s[tid] = wts[e * T_TOK + r];
  }
  __syncthreads();

  int lane = tid & 63, wid = tid >> 6;
  int sr = lane >> 3;
  int sg = (lane & 7) ^ sr;
  // staging: each wave: 2 A-insts (rows wid*16..+15), 2 B-insts (rows wid*16..+15)
  const unsigned short* a_src[2];
  #pragma unroll
  for (int t = 0; t < 2; t++)
    a_src[t] = H + (size_t)rid_s[wid * 16 + t * 8 + sr] * F_DIM + sg * 8;
  const unsigned short* b_src =
      W2t + ((size_t)e * D_DIM + nt * 128 + wid * 16 + sr) * F_DIM + sg * 8;

  // compute: 4x2 wave grid, wave owns 32 rows x 64 cols (32 acc regs)
  int wm = (wid >> 1) * 32, wn = (wid & 1) * 64;
  int frow = lane & 15;
  int fk = lane >> 4;

  f32x4 acc[2][4];
  #pragma unroll
  for (int mf = 0; mf < 2; mf++)
    #pragma unroll
    for (int nf = 0; nf < 4; nf++) {
      f32x4 z = {0.f, 0.f, 0.f, 0.f};
      acc[mf][nf] = z;
    }

  for (int k0 = 0; k0 < F_DIM; k0 += 64) {
    #pragma unroll
    for (int t = 0; t < 2; t++) {
      gload16(a_src[t] + k0, &As[(wid * 16 + t * 8) * 64]);
      gload16(b_src + (size_t)(t * 8) * F_DIM + k0, &Bs[(wid * 16 + t * 8) * 64]);
    }
    __syncthreads();
    #pragma unroll
    for (int kc = 0; kc < 2; kc++) {
      int gk = kc * 4 + fk;
      bf16x8 a[2], b[4];
      #pragma unroll
      for (int mf = 0; mf < 2; mf++) {
        int m = wm + mf * 16 + frow;
        a[mf] = *(const bf16x8*)&As[m * 64 + ((gk ^ (m & 7)) * 8)];
      }
      #pragma unroll
      for (int nf = 0; nf < 4; nf++) {
        int n = wn + nf * 16 + frow;
        b[nf] = *(const bf16x8*)&Bs[n * 64 + ((gk ^ (n & 7)) * 8)];
      }
      #pragma unroll
      for (int mf = 0; mf < 2; mf++)
        #pragma unroll
        for (int nf = 0; nf < 4; nf++)
          acc[mf][nf] = mfma16(a[mf], b[nf], acc[mf][nf]);
    }
    __syncthreads();
  }

  #pragma unroll
  for (int mf = 0; mf < 2; mf++) {
    #pragma unroll
    for (int i = 0; i < 4; i++) {
      int m = wm + mf * 16 + fk * 4 + i;
      if (base + m < cnt) {
        int tok = rid_s[m] >> 1;
        float w = wt_s[m];
        float* orow = out + (size_t)tok * D_DIM + nt * 128 + wn;
        #pragma unroll
        for (int nf = 0; nf < 4; nf++)
          atomicAdd(&orow[nf * 16 + frow], acc[mf][nf][i] * w);
      }
    }
  }
}

extern "C" void kernel_launch(void* const* d_in, const int* in_sizes, int n_in,
                              void* d_out, int out_size, void* d_ws, size_t ws_size,
                              hipStream_t stream) {
  const float* x  = (const float*)d_in[0];
  const float* gw = (const float*)d_in[1];
  const float* w1 = (const float*)d_in[2];
  const float* w2 = (const float*)d_in[3];
  const float* w3 = (const float*)d_in[4];
  float* out = (float*)d_out;

  char* ws = (char*)d_ws;
  const size_t LISTB = (size_t)E_NUM * T_TOK * 4;
  size_t o_counts = 0;
  size_t o_tiles  = 256;
  size_t o_list   = 2048;
  size_t o_wts    = o_list + LISTB;
  size_t o_Xb     = o_wts + LISTB;
  size_t o_W1t    = o_Xb + (size_t)T_TOK * D_DIM * 2;
  size_t wt_sz    = (size_t)E_NUM * F_DIM * D_DIM * 2;
  size_t o_W3t    = o_W1t + wt_sz;
  size_t o_W2t    = o_W3t + wt_sz;
  size_t o_H      = o_W2t + wt_sz;

  int* counts = (int*)(ws + o_counts);
  int4* tiles = (int4*)(ws + o_tiles);
  int* list   = (int*)(ws + o_list);
  float* wts  = (float*)(ws + o_wts);
  unsigned short* Xb  = (unsigned short*)(ws + o_Xb);
  unsigned short* W1t = (unsigned short*)(ws + o_W1t);
  unsigned short* W3t = (unsigned short*)(ws + o_W3t);
  unsigned short* W2t = (unsigned short*)(ws + o_W2t);
  unsigned short* H   = (unsigned short*)(ws + o_H);

  hipMemsetAsync(counts, 0, 256, stream);
  hipMemsetAsync(out, 0, (size_t)out_size * 4, stream);

  transpose_cvt_kernel<<<dim3(F_DIM / 64, D_DIM / 64, E_NUM), 256, 0, stream>>>(w1, W1t, D_DIM, F_DIM);
  transpose_cvt_kernel<<<dim3(F_DIM / 64, D_DIM / 64, E_NUM), 256, 0, stream>>>(w3, W3t, D_DIM, F_DIM);
  transpose_cvt_kernel<<<dim3(D_DIM / 64, F_DIM / 64, E_NUM), 256, 0, stream>>>(w2, W2t, F_DIM, D_DIM);

  router_kernel<<<dim3(T_TOK / 4), 256, 0, stream>>>(x, gw, counts, list, wts, Xb);
  tiles_kernel<<<dim3(1), 64, 0, stream>>>(counts, tiles);

  gemm1_kernel<<<dim3(F_DIM / 64, MAX_TILES), 512, 0, stream>>>(
      Xb, W1t, W3t, tiles, list, H);
  gemm2_kernel<<<dim3(D_DIM / 128, MAX_TILES), 512, 0, stream>>>(
      H, W2t, tiles, list, wts, out);
}

// Round 7
// 344.129 us; speedup vs baseline: 1.1987x; 1.0162x over previous
//
#include <hip/hip_runtime.h>

#define T_TOK 4096
#define D_DIM 1024
#define F_DIM 2048
#define E_NUM 8
#define MAX_TILES 72

typedef __attribute__((ext_vector_type(8))) short bf16x8;
typedef __attribute__((ext_vector_type(4))) float f32x4;

__device__ __forceinline__ unsigned short f2bf(float f) {
  unsigned u = __builtin_bit_cast(unsigned, f);
  unsigned r = 0x7FFFu + ((u >> 16) & 1u);
  return (unsigned short)((u + r) >> 16);
}

__device__ __forceinline__ void gload16(const unsigned short* g, unsigned short* l) {
  __builtin_amdgcn_global_load_lds(
      (const __attribute__((address_space(1))) unsigned int*)g,
      (__attribute__((address_space(3))) unsigned int*)l, 16, 0, 0);
}

__device__ __forceinline__ f32x4 mfma16(bf16x8 a, bf16x8 b, f32x4 c) {
  return __builtin_amdgcn_mfma_f32_16x16x32_bf16(a, b, c, 0, 0, 0);
}

#define VMCNT(N) asm volatile("s_waitcnt vmcnt(" #N ")" ::: "memory")
#define BAR() __builtin_amdgcn_s_barrier()

// ---------------- merged transpose+convert for w1,w3,w2 ----------------
// z: 0..7 -> w1 [D][F]->[F][D]; 8..15 -> w3; 16..23 -> w2 [F][D]->[D][F]
__global__ __launch_bounds__(256) void transpose_all_kernel(
    const float* __restrict__ w1, const float* __restrict__ w3,
    const float* __restrict__ w2,
    unsigned short* __restrict__ W1t, unsigned short* __restrict__ W3t,
    unsigned short* __restrict__ W2t) {
  __shared__ float tile[64][65];
  int z = blockIdx.z;
  int which = z >> 3, e = z & 7;
  const float* src; unsigned short* dst; int M, N;
  if (which == 0)      { src = w1; dst = W1t; M = D_DIM; N = F_DIM; }
  else if (which == 1) { src = w3; dst = W3t; M = D_DIM; N = F_DIM; }
  else                 { src = w2; dst = W2t; M = F_DIM; N = D_DIM; }
  src += (size_t)e * M * N; dst += (size_t)e * M * N;
  int bid = blockIdx.y * gridDim.x + blockIdx.x;   // 0..511
  int nbx = N / 64;
  int i0 = (bid / nbx) * 64, j0 = (bid % nbx) * 64;
  int tid = threadIdx.x;
  int lr = tid >> 4;           // 0..15
  int lc = (tid & 15) * 4;     // 0..60
  #pragma unroll
  for (int p = 0; p < 4; p++) {
    int row = p * 16 + lr;
    float4 v = *(const float4*)&src[(size_t)(i0 + row) * N + j0 + lc];
    tile[row][lc + 0] = v.x; tile[row][lc + 1] = v.y;
    tile[row][lc + 2] = v.z; tile[row][lc + 3] = v.w;
  }
  __syncthreads();
  #pragma unroll
  for (int p = 0; p < 4; p++) {
    int orow = p * 16 + lr;
    unsigned short b0 = f2bf(tile[lc + 0][orow]);
    unsigned short b1 = f2bf(tile[lc + 1][orow]);
    unsigned short b2 = f2bf(tile[lc + 2][orow]);
    unsigned short b3 = f2bf(tile[lc + 3][orow]);
    uint2 o;
    o.x = b0 | ((unsigned)b1 << 16);
    o.y = b2 | ((unsigned)b3 << 16);
    *(uint2*)&dst[(size_t)(j0 + orow) * M + i0 + lc] = o;
  }
}

// ---------------- router (+ fused x->bf16 convert): 1 wave per token ----------------
__global__ __launch_bounds__(256) void router_kernel(const float* __restrict__ x,
                                                     const float* __restrict__ gw,
                                                     int* __restrict__ counts,
                                                     int* __restrict__ list,
                                                     float* __restrict__ wts,
                                                     unsigned short* __restrict__ Xb) {
  int lane = threadIdx.x & 63;
  int t = blockIdx.x * 4 + (threadIdx.x >> 6);
  float acc[E_NUM];
  #pragma unroll
  for (int e = 0; e < E_NUM; e++) acc[e] = 0.f;
  const float* xr = x + (size_t)t * D_DIM;
  unsigned short* xbr = Xb + (size_t)t * D_DIM;
  #pragma unroll
  for (int j = 0; j < D_DIM / 64; j++) {
    int d = lane + 64 * j;
    float xv = xr[d];
    xbr[d] = f2bf(xv);
    const float4* g = reinterpret_cast<const float4*>(gw + (size_t)d * E_NUM);
    float4 g0 = g[0], g1 = g[1];
    acc[0] += xv * g0.x; acc[1] += xv * g0.y; acc[2] += xv * g0.z; acc[3] += xv * g0.w;
    acc[4] += xv * g1.x; acc[5] += xv * g1.y; acc[6] += xv * g1.z; acc[7] += xv * g1.w;
  }
  #pragma unroll
  for (int e = 0; e < E_NUM; e++) {
    #pragma unroll
    for (int off = 32; off > 0; off >>= 1) acc[e] += __shfl_xor(acc[e], off);
  }
  if (lane == 0) {
    int e1 = 0; float l1 = acc[0];
    #pragma unroll
    for (int e = 1; e < E_NUM; e++) { if (acc[e] > l1) { l1 = acc[e]; e1 = e; } }
    int e2 = -1; float l2 = -1e30f;
    #pragma unroll
    for (int e = 0; e < E_NUM; e++) { if (e != e1 && acc[e] > l2) { l2 = acc[e]; e2 = e; } }
    float wa = 1.f / (1.f + expf(l2 - l1));
    float wb = 1.f / (1.f + expf(l1 - l2));
    int p1 = atomicAdd(&counts[e1], 1);
    list[e1 * T_TOK + p1] = t * 2;     wts[e1 * T_TOK + p1] = wa;
    int p2 = atomicAdd(&counts[e2], 1);
    list[e2 * T_TOK + p2] = t * 2 + 1; wts[e2 * T_TOK + p2] = wb;
  }
}

// ---------------- tile descriptors: (expert, base, cnt), sentinel e=-1 ----------------
__global__ void tiles_kernel(const int* __restrict__ counts, int4* __restrict__ tiles) {
  if (threadIdx.x == 0) {
    int n = 0;
    for (int e = 0; e < E_NUM; e++) {
      int cnt = counts[e];
      for (int b = 0; b < cnt; b += 128) {
        int4 t; t.x = e; t.y = b; t.z = cnt; t.w = 0;
        tiles[n++] = t;
      }
    }
    for (; n < MAX_TILES; n++) {
      int4 t; t.x = -1; t.y = 0; t.z = 0; t.w = 0;
      tiles[n] = t;
    }
  }
}

// ---------------- GEMM1: H = silu(X@w1)*(X@w3), 128x64 dual tile, 8 waves,
//                  counted-vmcnt 2-phase pipeline ----------------
__global__ __launch_bounds__(512, 4) void gemm1_kernel(
    const unsigned short* __restrict__ Xb,   // [T][D] bf16
    const unsigned short* __restrict__ W1t,  // [E][F][D] bf16
    const unsigned short* __restrict__ W3t,  // [E][F][D] bf16
    const int4* __restrict__ tiles, const int* __restrict__ list,
    unsigned short* __restrict__ H) {        // [T*2][F] bf16
  __shared__ unsigned short As[2][128 * 64];   // 32 KB
  __shared__ unsigned short B1s[2][64 * 64];   // 16 KB
  __shared__ unsigned short B3s[2][64 * 64];   // 16 KB
  __shared__ int rid_s[128];

  int4 td = tiles[blockIdx.y];
  int e = td.x;
  if (e < 0) return;
  int base = td.y, cnt = td.z;
  int nt = blockIdx.x;          // 0..31 over F/64
  int tid = threadIdx.x;

  if (tid < 128) {
    int r = base + tid; if (r > cnt - 1) r = cnt - 1;
    rid_s[tid] = list[e * T_TOK + r];
  }
  __syncthreads();

  int lane = tid & 63, wid = tid >> 6;       // wid 0..7
  int sr = lane >> 3;                        // 0..7 row within 8-row group
  int sg = (lane & 7) ^ sr;                  // pre-swizzled source granule
  const unsigned short* a_src[2];
  #pragma unroll
  for (int t = 0; t < 2; t++)
    a_src[t] = Xb + (size_t)(rid_s[wid * 16 + t * 8 + sr] >> 1) * D_DIM + sg * 8;
  const unsigned short* b1_src =
      W1t + ((size_t)e * F_DIM + nt * 64 + wid * 8 + sr) * D_DIM + sg * 8;
  const unsigned short* b3_src =
      W3t + ((size_t)e * F_DIM + nt * 64 + wid * 8 + sr) * D_DIM + sg * 8;

  int wm = (wid >> 1) * 32, wn = (wid & 1) * 32;
  int frow = lane & 15;
  int fk = lane >> 4;

  f32x4 acc1[2][2], acc3[2][2];
  #pragma unroll
  for (int mf = 0; mf < 2; mf++)
    #pragma unroll
    for (int nf = 0; nf < 2; nf++) {
      f32x4 z = {0.f, 0.f, 0.f, 0.f};
      acc1[mf][nf] = z; acc3[mf][nf] = z;
    }

  auto stage = [&](int b, int k0) {          // 4 vmem ops per wave
    #pragma unroll
    for (int t = 0; t < 2; t++)
      gload16(a_src[t] + k0, &As[b][(wid * 16 + t * 8) * 64]);
    gload16(b1_src + k0, &B1s[b][(wid * 8) * 64]);
    gload16(b3_src + k0, &B3s[b][(wid * 8) * 64]);
  };
  auto compute = [&](int b) {
    #pragma unroll
    for (int kc = 0; kc < 2; kc++) {
      int gk = kc * 4 + fk;
      bf16x8 a[2], b1[2], b3[2];
      #pragma unroll
      for (int mf = 0; mf < 2; mf++) {
        int m = wm + mf * 16 + frow;
        a[mf] = *(const bf16x8*)&As[b][m * 64 + ((gk ^ (m & 7)) * 8)];
      }
      #pragma unroll
      for (int nf = 0; nf < 2; nf++) {
        int n = wn + nf * 16 + frow;
        b1[nf] = *(const bf16x8*)&B1s[b][n * 64 + ((gk ^ (n & 7)) * 8)];
        b3[nf] = *(const bf16x8*)&B3s[b][n * 64 + ((gk ^ (n & 7)) * 8)];
      }
      #pragma unroll
      for (int mf = 0; mf < 2; mf++)
        #pragma unroll
        for (int nf = 0; nf < 2; nf++) {
          acc1[mf][nf] = mfma16(a[mf], b1[nf], acc1[mf][nf]);
          acc3[mf][nf] = mfma16(a[mf], b3[nf], acc3[mf][nf]);
        }
    }
  };

  stage(0, 0);
  int cur = 0;
  #pragma unroll 1
  for (int k0 = 64; k0 < D_DIM; k0 += 64) {
    stage(cur ^ 1, k0);          // 8 in flight
    VMCNT(4);                    // own cur-loads retired; nxt stays in flight
    BAR();                       // all waves' cur-writes landed
    compute(cur);
    BAR();                       // all reads of cur done -> next iter may overwrite
    cur ^= 1;
  }
  VMCNT(0);
  BAR();
  compute(cur);

  #pragma unroll
  for (int mf = 0; mf < 2; mf++) {
    #pragma unroll
    for (int i = 0; i < 4; i++) {
      int m = wm + mf * 16 + fk * 4 + i;
      if (base + m < cnt) {
        int rid = rid_s[m];
        unsigned short* hrow = H + (size_t)rid * F_DIM + nt * 64 + wn;
        #pragma unroll
        for (int nf = 0; nf < 2; nf++) {
          float z = acc1[mf][nf][i];
          float u = acc3[mf][nf][i];
          hrow[nf * 16 + frow] = f2bf((z / (1.f + expf(-z))) * u);
        }
      }
    }
  }
}

// ---------------- GEMM2: out += (H @ w2) * weight, 128x128, 8 waves,
//                  counted-vmcnt 2-phase pipeline ----------------
__global__ __launch_bounds__(512, 4) void gemm2_kernel(
    const unsigned short* __restrict__ H,    // [T*2][F] bf16
    const unsigned short* __restrict__ W2t,  // [E][D][F] bf16
    const int4* __restrict__ tiles, const int* __restrict__ list,
    const float* __restrict__ wts,
    float* __restrict__ out) {               // [T][D] fp32 (pre-zeroed)
  __shared__ unsigned short As[2][128 * 64];   // 32 KB
  __shared__ unsigned short Bs[2][128 * 64];   // 32 KB
  __shared__ int rid_s[128];
  __shared__ float wt_s[128];

  int4 td = tiles[blockIdx.y];
  int e = td.x;
  if (e < 0) return;
  int base = td.y, cnt = td.z;
  int nt = blockIdx.x;   // 0..7 over D/128
  int tid = threadIdx.x;

  if (tid < 128) {
    int r = base + tid; if (r > cnt - 1) r = cnt - 1;
    rid_s[tid] = list[e * T_TOK + r];
    wt_s[tid] = wts[e * T_TOK + r];
  }
  __syncthreads();

  int lane = tid & 63, wid = tid >> 6;
  int sr = lane >> 3;
  int sg = (lane & 7) ^ sr;
  const unsigned short* a_src[2];
  #pragma unroll
  for (int t = 0; t < 2; t++)
    a_src[t] = H + (size_t)rid_s[wid * 16 + t * 8 + sr] * F_DIM + sg * 8;
  const unsigned short* b_src =
      W2t + ((size_t)e * D_DIM + nt * 128 + wid * 16 + sr) * F_DIM + sg * 8;

  int wm = (wid >> 1) * 32, wn = (wid & 1) * 64;
  int frow = lane & 15;
  int fk = lane >> 4;

  f32x4 acc[2][4];
  #pragma unroll
  for (int mf = 0; mf < 2; mf++)
    #pragma unroll
    for (int nf = 0; nf < 4; nf++) {
      f32x4 z = {0.f, 0.f, 0.f, 0.f};
      acc[mf][nf] = z;
    }

  auto stage = [&](int b, int k0) {          // 4 vmem ops per wave
    #pragma unroll
    for (int t = 0; t < 2; t++) {
      gload16(a_src[t] + k0, &As[b][(wid * 16 + t * 8) * 64]);
      gload16(b_src + (size_t)(t * 8) * F_DIM + k0, &Bs[b][(wid * 16 + t * 8) * 64]);
    }
  };
  auto compute = [&](int bb) {
    #pragma unroll
    for (int kc = 0; kc < 2; kc++) {
      int gk = kc * 4 + fk;
      bf16x8 a[2], b[4];
      #pragma unroll
      for (int mf = 0; mf < 2; mf++) {
        int m = wm + mf * 16 + frow;
        a[mf] = *(const bf16x8*)&As[bb][m * 64 + ((gk ^ (m & 7)) * 8)];
      }
      #pragma unroll
      for (int nf = 0; nf < 4; nf++) {
        int n = wn + nf * 16 + frow;
        b[nf] = *(const bf16x8*)&Bs[bb][n * 64 + ((gk ^ (n & 7)) * 8)];
      }
      #pragma unroll
      for (int mf = 0; mf < 2; mf++)
        #pragma unroll
        for (int nf = 0; nf < 4; nf++)
          acc[mf][nf] = mfma16(a[mf], b[nf], acc[mf][nf]);
    }
  };

  stage(0, 0);
  int cur = 0;
  #pragma unroll 1
  for (int k0 = 64; k0 < F_DIM; k0 += 64) {
    stage(cur ^ 1, k0);
    VMCNT(4);
    BAR();
    compute(cur);
    BAR();
    cur ^= 1;
  }
  VMCNT(0);
  BAR();
  compute(cur);

  #pragma unroll
  for (int mf = 0; mf < 2; mf++) {
    #pragma unroll
    for (int i = 0; i < 4; i++) {
      int m = wm + mf * 16 + fk * 4 + i;
      if (base + m < cnt) {
        int tok = rid_s[m] >> 1;
        float w = wt_s[m];
        float* orow = out + (size_t)tok * D_DIM + nt * 128 + wn;
        #pragma unroll
        for (int nf = 0; nf < 4; nf++)
          atomicAdd(&orow[nf * 16 + frow], acc[mf][nf][i] * w);
      }
    }
  }
}

extern "C" void kernel_launch(void* const* d_in, const int* in_sizes, int n_in,
                              void* d_out, int out_size, void* d_ws, size_t ws_size,
                              hipStream_t stream) {
  const float* x  = (const float*)d_in[0];
  const float* gw = (const float*)d_in[1];
  const float* w1 = (const float*)d_in[2];
  const float* w2 = (const float*)d_in[3];
  const float* w3 = (const float*)d_in[4];
  float* out = (float*)d_out;

  char* ws = (char*)d_ws;
  const size_t LISTB = (size_t)E_NUM * T_TOK * 4;
  size_t o_counts = 0;
  size_t o_tiles  = 256;
  size_t o_list   = 2048;
  size_t o_wts    = o_list + LISTB;
  size_t o_Xb     = o_wts + LISTB;
  size_t o_W1t    = o_Xb + (size_t)T_TOK * D_DIM * 2;
  size_t wt_sz    = (size_t)E_NUM * F_DIM * D_DIM * 2;
  size_t o_W3t    = o_W1t + wt_sz;
  size_t o_W2t    = o_W3t + wt_sz;
  size_t o_H      = o_W2t + wt_sz;

  int* counts = (int*)(ws + o_counts);
  int4* tiles = (int4*)(ws + o_tiles);
  int* list   = (int*)(ws + o_list);
  float* wts  = (float*)(ws + o_wts);
  unsigned short* Xb  = (unsigned short*)(ws + o_Xb);
  unsigned short* W1t = (unsigned short*)(ws + o_W1t);
  unsigned short* W3t = (unsigned short*)(ws + o_W3t);
  unsigned short* W2t = (unsigned short*)(ws + o_W2t);
  unsigned short* H   = (unsigned short*)(ws + o_H);

  hipMemsetAsync(counts, 0, 256, stream);
  hipMemsetAsync(out, 0, (size_t)out_size * 4, stream);

  transpose_all_kernel<<<dim3(32, 16, 24), 256, 0, stream>>>(
      w1, w3, w2, W1t, W3t, W2t);

  router_kernel<<<dim3(T_TOK / 4), 256, 0, stream>>>(x, gw, counts, list, wts, Xb);
  tiles_kernel<<<dim3(1), 64, 0, stream>>>(counts, tiles);

  gemm1_kernel<<<dim3(F_DIM / 64, MAX_TILES), 512, 0, stream>>>(
      Xb, W1t, W3t, tiles, list, H);
  gemm2_kernel<<<dim3(D_DIM / 128, MAX_TILES), 512, 0, stream>>>(
      H, W2t, tiles, list, wts, out);
}

// Round 8
// 321.749 us; speedup vs baseline: 1.2821x; 1.0696x over previous
//
#include <hip/hip_runtime.h>

#define T_TOK 4096
#define D_DIM 1024
#define F_DIM 2048
#define E_NUM 8
#define MAX_TILES 136

typedef __attribute__((ext_vector_type(8))) short bf16x8;
typedef __attribute__((ext_vector_type(4))) float f32x4;

__device__ __forceinline__ unsigned short f2bf(float f) {
  unsigned u = __builtin_bit_cast(unsigned, f);
  unsigned r = 0x7FFFu + ((u >> 16) & 1u);
  return (unsigned short)((u + r) >> 16);
}

__device__ __forceinline__ void gload16(const unsigned short* g, unsigned short* l) {
  __builtin_amdgcn_global_load_lds(
      (const __attribute__((address_space(1))) unsigned int*)g,
      (__attribute__((address_space(3))) unsigned int*)l, 16, 0, 0);
}

__device__ __forceinline__ f32x4 mfma16(bf16x8 a, bf16x8 b, f32x4 c) {
  return __builtin_amdgcn_mfma_f32_16x16x32_bf16(a, b, c, 0, 0, 0);
}

// ---------------- merged transpose+convert for w1,w3,w2 ----------------
__global__ __launch_bounds__(256) void transpose_all_kernel(
    const float* __restrict__ w1, const float* __restrict__ w3,
    const float* __restrict__ w2,
    unsigned short* __restrict__ W1t, unsigned short* __restrict__ W3t,
    unsigned short* __restrict__ W2t) {
  __shared__ float tile[64][65];
  int z = blockIdx.z;
  int which = z >> 3, e = z & 7;
  const float* src; unsigned short* dst; int M, N;
  if (which == 0)      { src = w1; dst = W1t; M = D_DIM; N = F_DIM; }
  else if (which == 1) { src = w3; dst = W3t; M = D_DIM; N = F_DIM; }
  else                 { src = w2; dst = W2t; M = F_DIM; N = D_DIM; }
  src += (size_t)e * M * N; dst += (size_t)e * M * N;
  int bid = blockIdx.y * gridDim.x + blockIdx.x;
  int nbx = N / 64;
  int i0 = (bid / nbx) * 64, j0 = (bid % nbx) * 64;
  int tid = threadIdx.x;
  int lr = tid >> 4;
  int lc = (tid & 15) * 4;
  #pragma unroll
  for (int p = 0; p < 4; p++) {
    int row = p * 16 + lr;
    float4 v = *(const float4*)&src[(size_t)(i0 + row) * N + j0 + lc];
    tile[row][lc + 0] = v.x; tile[row][lc + 1] = v.y;
    tile[row][lc + 2] = v.z; tile[row][lc + 3] = v.w;
  }
  __syncthreads();
  #pragma unroll
  for (int p = 0; p < 4; p++) {
    int orow = p * 16 + lr;
    unsigned short b0 = f2bf(tile[lc + 0][orow]);
    unsigned short b1 = f2bf(tile[lc + 1][orow]);
    unsigned short b2 = f2bf(tile[lc + 2][orow]);
    unsigned short b3 = f2bf(tile[lc + 3][orow]);
    uint2 o;
    o.x = b0 | ((unsigned)b1 << 16);
    o.y = b2 | ((unsigned)b3 << 16);
    *(uint2*)&dst[(size_t)(j0 + orow) * M + i0 + lc] = o;
  }
}

// ---------------- router (+ fused x->bf16 convert): 1 wave per token ----------------
__global__ __launch_bounds__(256) void router_kernel(const float* __restrict__ x,
                                                     const float* __restrict__ gw,
                                                     int* __restrict__ counts,
                                                     int* __restrict__ list,
                                                     float* __restrict__ wts,
                                                     unsigned short* __restrict__ Xb) {
  int lane = threadIdx.x & 63;
  int t = blockIdx.x * 4 + (threadIdx.x >> 6);
  float acc[E_NUM];
  #pragma unroll
  for (int e = 0; e < E_NUM; e++) acc[e] = 0.f;
  const float* xr = x + (size_t)t * D_DIM;
  unsigned short* xbr = Xb + (size_t)t * D_DIM;
  #pragma unroll
  for (int j = 0; j < D_DIM / 64; j++) {
    int d = lane + 64 * j;
    float xv = xr[d];
    xbr[d] = f2bf(xv);
    const float4* g = reinterpret_cast<const float4*>(gw + (size_t)d * E_NUM);
    float4 g0 = g[0], g1 = g[1];
    acc[0] += xv * g0.x; acc[1] += xv * g0.y; acc[2] += xv * g0.z; acc[3] += xv * g0.w;
    acc[4] += xv * g1.x; acc[5] += xv * g1.y; acc[6] += xv * g1.z; acc[7] += xv * g1.w;
  }
  #pragma unroll
  for (int e = 0; e < E_NUM; e++) {
    #pragma unroll
    for (int off = 32; off > 0; off >>= 1) acc[e] += __shfl_xor(acc[e], off);
  }
  if (lane == 0) {
    int e1 = 0; float l1 = acc[0];
    #pragma unroll
    for (int e = 1; e < E_NUM; e++) { if (acc[e] > l1) { l1 = acc[e]; e1 = e; } }
    int e2 = -1; float l2 = -1e30f;
    #pragma unroll
    for (int e = 0; e < E_NUM; e++) { if (e != e1 && acc[e] > l2) { l2 = acc[e]; e2 = e; } }
    float wa = 1.f / (1.f + expf(l2 - l1));
    float wb = 1.f / (1.f + expf(l1 - l2));
    int p1 = atomicAdd(&counts[e1], 1);
    list[e1 * T_TOK + p1] = t * 2;     wts[e1 * T_TOK + p1] = wa;
    int p2 = atomicAdd(&counts[e2], 1);
    list[e2 * T_TOK + p2] = t * 2 + 1; wts[e2 * T_TOK + p2] = wb;
  }
}

// ---------------- tile descriptors (64-row granularity), sentinel e=-1 ----------------
__global__ void tiles_kernel(const int* __restrict__ counts, int4* __restrict__ tiles) {
  __shared__ int start[E_NUM + 1];
  int tid = threadIdx.x;  // 64 threads
  if (tid == 0) {
    int s = 0;
    for (int e = 0; e < E_NUM; e++) { start[e] = s; s += (counts[e] + 63) >> 6; }
    start[E_NUM] = s;
  }
  __syncthreads();
  int total = start[E_NUM];
  for (int n = tid; n < MAX_TILES; n += 64) {
    int4 t;
    if (n < total) {
      int e = 0;
      #pragma unroll
      for (int j = 1; j < E_NUM; j++) if (n >= start[j]) e = j;
      t.x = e; t.y = (n - start[e]) * 64; t.z = counts[e]; t.w = 0;
    } else {
      t.x = -1; t.y = 0; t.z = 0; t.w = 0;
    }
    tiles[n] = t;
  }
}

// ---------------- GEMM1: H = silu(X@w1)*(X@w3), 64x64 dual tile, 4 waves, 6 blocks/CU ----
__global__ __launch_bounds__(256, 4) void gemm1_kernel(
    const unsigned short* __restrict__ Xb,   // [T][D] bf16
    const unsigned short* __restrict__ W1t,  // [E][F][D] bf16
    const unsigned short* __restrict__ W3t,  // [E][F][D] bf16
    const int4* __restrict__ tiles, const int* __restrict__ list,
    unsigned short* __restrict__ H) {        // [T*2][F] bf16
  __shared__ unsigned short As[64 * 64];     // 8 KB
  __shared__ unsigned short B1s[64 * 64];    // 8 KB
  __shared__ unsigned short B3s[64 * 64];    // 8 KB
  __shared__ int rid_s[64];

  int4 td = tiles[blockIdx.y];
  int e = td.x;
  if (e < 0) return;
  int base = td.y, cnt = td.z;
  int nt = blockIdx.x;          // 0..31 over F/64
  int tid = threadIdx.x;

  if (tid < 64) {
    int r = base + tid; if (r > cnt - 1) r = cnt - 1;
    rid_s[tid] = list[e * T_TOK + r];
  }
  __syncthreads();

  int lane = tid & 63, wid = tid >> 6;       // wid 0..3
  int sr = lane >> 3;                        // 0..7
  int sg = (lane & 7) ^ sr;                  // pre-swizzled source granule
  // staging: each wave stages 16 rows of A, B1, B3 (2 insts each)
  const unsigned short* a_src[2];
  #pragma unroll
  for (int t = 0; t < 2; t++)
    a_src[t] = Xb + (size_t)(rid_s[wid * 16 + t * 8 + sr] >> 1) * D_DIM + sg * 8;
  const unsigned short *b1_src[2], *b3_src[2];
  #pragma unroll
  for (int t = 0; t < 2; t++) {
    size_t row = (size_t)e * F_DIM + nt * 64 + wid * 16 + t * 8 + sr;
    b1_src[t] = W1t + row * D_DIM + sg * 8;
    b3_src[t] = W3t + row * D_DIM + sg * 8;
  }

  // compute: 2x2 wave grid, wave owns 32x32 of BOTH branches
  int wm = (wid >> 1) * 32, wn = (wid & 1) * 32;
  int frow = lane & 15;
  int fk = lane >> 4;

  // hoisted LDS element offsets (loop-invariant; B1s/B3s share geometry)
  unsigned offA[2][2], offB[2][2];
  #pragma unroll
  for (int mf = 0; mf < 2; mf++)
    #pragma unroll
    for (int kc = 0; kc < 2; kc++) {
      int m = wm + mf * 16 + frow, gk = kc * 4 + fk;
      offA[mf][kc] = m * 64 + ((gk ^ (m & 7)) * 8);
    }
  #pragma unroll
  for (int nf = 0; nf < 2; nf++)
    #pragma unroll
    for (int kc = 0; kc < 2; kc++) {
      int n = wn + nf * 16 + frow, gk = kc * 4 + fk;
      offB[nf][kc] = n * 64 + ((gk ^ (n & 7)) * 8);
    }

  f32x4 acc1[2][2], acc3[2][2];
  #pragma unroll
  for (int mf = 0; mf < 2; mf++)
    #pragma unroll
    for (int nf = 0; nf < 2; nf++) {
      f32x4 z = {0.f, 0.f, 0.f, 0.f};
      acc1[mf][nf] = z; acc3[mf][nf] = z;
    }

  #pragma unroll 1
  for (int k0 = 0; k0 < D_DIM; k0 += 64) {
    #pragma unroll
    for (int t = 0; t < 2; t++) {
      gload16(a_src[t] + k0, &As[(wid * 16 + t * 8) * 64]);
      gload16(b1_src[t] + k0, &B1s[(wid * 16 + t * 8) * 64]);
      gload16(b3_src[t] + k0, &B3s[(wid * 16 + t * 8) * 64]);
    }
    __syncthreads();
    #pragma unroll
    for (int kc = 0; kc < 2; kc++) {
      bf16x8 a[2], b1[2], b3[2];
      #pragma unroll
      for (int mf = 0; mf < 2; mf++) a[mf] = *(const bf16x8*)&As[offA[mf][kc]];
      #pragma unroll
      for (int nf = 0; nf < 2; nf++) {
        b1[nf] = *(const bf16x8*)&B1s[offB[nf][kc]];
        b3[nf] = *(const bf16x8*)&B3s[offB[nf][kc]];
      }
      #pragma unroll
      for (int mf = 0; mf < 2; mf++)
        #pragma unroll
        for (int nf = 0; nf < 2; nf++) {
          acc1[mf][nf] = mfma16(a[mf], b1[nf], acc1[mf][nf]);
          acc3[mf][nf] = mfma16(a[mf], b3[nf], acc3[mf][nf]);
        }
    }
    __syncthreads();
  }

  #pragma unroll
  for (int mf = 0; mf < 2; mf++) {
    #pragma unroll
    for (int i = 0; i < 4; i++) {
      int m = wm + mf * 16 + fk * 4 + i;
      if (base + m < cnt) {
        int rid = rid_s[m];
        unsigned short* hrow = H + (size_t)rid * F_DIM + nt * 64 + wn;
        #pragma unroll
        for (int nf = 0; nf < 2; nf++) {
          float z = acc1[mf][nf][i];
          float u = acc3[mf][nf][i];
          hrow[nf * 16 + frow] = f2bf((z / (1.f + expf(-z))) * u);
        }
      }
    }
  }
}

// ---------------- GEMM2: out += (H @ w2) * weight, 64x128 tile, 4 waves, 6 blocks/CU ------
__global__ __launch_bounds__(256, 4) void gemm2_kernel(
    const unsigned short* __restrict__ H,    // [T*2][F] bf16
    const unsigned short* __restrict__ W2t,  // [E][D][F] bf16
    const int4* __restrict__ tiles, const int* __restrict__ list,
    const float* __restrict__ wts,
    float* __restrict__ out) {               // [T][D] fp32 (pre-zeroed)
  __shared__ unsigned short As[64 * 64];     // 8 KB
  __shared__ unsigned short Bs[128 * 64];    // 16 KB
  __shared__ int rid_s[64];
  __shared__ float wt_s[64];

  int4 td = tiles[blockIdx.y];
  int e = td.x;
  if (e < 0) return;
  int base = td.y, cnt = td.z;
  int nt = blockIdx.x;   // 0..7 over D/128
  int tid = threadIdx.x;

  if (tid < 64) {
    int r = base + tid; if (r > cnt - 1) r = cnt - 1;
    rid_s[tid] = list[e * T_TOK + r];
    wt_s[tid] = wts[e * T_TOK + r];
  }
  __syncthreads();

  int lane = tid & 63, wid = tid >> 6;
  int sr = lane >> 3;
  int sg = (lane & 7) ^ sr;
  // staging: A 64 rows (2 insts/wave), B 128 rows (4 insts/wave)
  const unsigned short* a_src[2];
  #pragma unroll
  for (int t = 0; t < 2; t++)
    a_src[t] = H + (size_t)rid_s[wid * 16 + t * 8 + sr] * F_DIM + sg * 8;
  const unsigned short* b_src[4];
  #pragma unroll
  for (int t = 0; t < 4; t++)
    b_src[t] = W2t + ((size_t)e * D_DIM + nt * 128 + wid * 32 + t * 8 + sr) * F_DIM + sg * 8;

  // compute: 2x2 wave grid, wave owns 32 rows x 64 cols
  int wm = (wid >> 1) * 32, wn = (wid & 1) * 64;
  int frow = lane & 15;
  int fk = lane >> 4;

  unsigned offA[2][2], offB[4][2];
  #pragma unroll
  for (int mf = 0; mf < 2; mf++)
    #pragma unroll
    for (int kc = 0; kc < 2; kc++) {
      int m = wm + mf * 16 + frow, gk = kc * 4 + fk;
      offA[mf][kc] = m * 64 + ((gk ^ (m & 7)) * 8);
    }
  #pragma unroll
  for (int nf = 0; nf < 4; nf++)
    #pragma unroll
    for (int kc = 0; kc < 2; kc++) {
      int n = wn + nf * 16 + frow, gk = kc * 4 + fk;
      offB[nf][kc] = n * 64 + ((gk ^ (n & 7)) * 8);
    }

  f32x4 acc[2][4];
  #pragma unroll
  for (int mf = 0; mf < 2; mf++)
    #pragma unroll
    for (int nf = 0; nf < 4; nf++) {
      f32x4 z = {0.f, 0.f, 0.f, 0.f};
      acc[mf][nf] = z;
    }

  #pragma unroll 1
  for (int k0 = 0; k0 < F_DIM; k0 += 64) {
    #pragma unroll
    for (int t = 0; t < 2; t++)
      gload16(a_src[t] + k0, &As[(wid * 16 + t * 8) * 64]);
    #pragma unroll
    for (int t = 0; t < 4; t++)
      gload16(b_src[t] + k0, &Bs[(wid * 32 + t * 8) * 64]);
    __syncthreads();
    #pragma unroll
    for (int kc = 0; kc < 2; kc++) {
      bf16x8 a[2], b[4];
      #pragma unroll
      for (int mf = 0; mf < 2; mf++) a[mf] = *(const bf16x8*)&As[offA[mf][kc]];
      #pragma unroll
      for (int nf = 0; nf < 4; nf++) b[nf] = *(const bf16x8*)&Bs[offB[nf][kc]];
      #pragma unroll
      for (int mf = 0; mf < 2; mf++)
        #pragma unroll
        for (int nf = 0; nf < 4; nf++)
          acc[mf][nf] = mfma16(a[mf], b[nf], acc[mf][nf]);
    }
    __syncthreads();
  }

  #pragma unroll
  for (int mf = 0; mf < 2; mf++) {
    #pragma unroll
    for (int i = 0; i < 4; i++) {
      int m = wm + mf * 16 + fk * 4 + i;
      if (base + m < cnt) {
        int tok = rid_s[m] >> 1;
        float w = wt_s[m];
        float* orow = out + (size_t)tok * D_DIM + nt * 128 + wn;
        #pragma unroll
        for (int nf = 0; nf < 4; nf++)
          atomicAdd(&orow[nf * 16 + frow], acc[mf][nf][i] * w);
      }
    }
  }
}

extern "C" void kernel_launch(void* const* d_in, const int* in_sizes, int n_in,
                              void* d_out, int out_size, void* d_ws, size_t ws_size,
                              hipStream_t stream) {
  const float* x  = (const float*)d_in[0];
  const float* gw = (const float*)d_in[1];
  const float* w1 = (const float*)d_in[2];
  const float* w2 = (const float*)d_in[3];
  const float* w3 = (const float*)d_in[4];
  float* out = (float*)d_out;

  char* ws = (char*)d_ws;
  const size_t LISTB = (size_t)E_NUM * T_TOK * 4;
  size_t o_counts = 0;
  size_t o_tiles  = 256;                                   // int4[136] = 2176 B
  size_t o_list   = 4096;
  size_t o_wts    = o_list + LISTB;
  size_t o_Xb     = o_wts + LISTB;
  size_t o_W1t    = o_Xb + (size_t)T_TOK * D_DIM * 2;
  size_t wt_sz    = (size_t)E_NUM * F_DIM * D_DIM * 2;
  size_t o_W3t    = o_W1t + wt_sz;
  size_t o_W2t    = o_W3t + wt_sz;
  size_t o_H      = o_W2t + wt_sz;

  int* counts = (int*)(ws + o_counts);
  int4* tiles = (int4*)(ws + o_tiles);
  int* list   = (int*)(ws + o_list);
  float* wts  = (float*)(ws + o_wts);
  unsigned short* Xb  = (unsigned short*)(ws + o_Xb);
  unsigned short* W1t = (unsigned short*)(ws + o_W1t);
  unsigned short* W3t = (unsigned short*)(ws + o_W3t);
  unsigned short* W2t = (unsigned short*)(ws + o_W2t);
  unsigned short* H   = (unsigned short*)(ws + o_H);

  hipMemsetAsync(counts, 0, 256, stream);
  hipMemsetAsync(out, 0, (size_t)out_size * 4, stream);

  transpose_all_kernel<<<dim3(32, 16, 24), 256, 0, stream>>>(
      w1, w3, w2, W1t, W3t, W2t);

  router_kernel<<<dim3(T_TOK / 4), 256, 0, stream>>>(x, gw, counts, list, wts, Xb);
  tiles_kernel<<<dim3(1), 64, 0, stream>>>(counts, tiles);

  gemm1_kernel<<<dim3(F_DIM / 64, MAX_TILES), 256, 0, stream>>>(
      Xb, W1t, W3t, tiles, list, H);
  gemm2_kernel<<<dim3(D_DIM / 128, MAX_TILES), 256, 0, stream>>>(
      H, W2t, tiles, list, wts, out);
}

// Round 9
// 241.132 us; speedup vs baseline: 1.7108x; 1.3343x over previous
//
#include <hip/hip_runtime.h>

#define T_TOK 4096
#define D_DIM 1024
#define F_DIM 2048
#define E_NUM 8
#define MAX_TILES 136

typedef __attribute__((ext_vector_type(8))) short bf16x8;
typedef __attribute__((ext_vector_type(4))) float f32x4;

__device__ __forceinline__ unsigned short f2bf(float f) {
  unsigned u = __builtin_bit_cast(unsigned, f);
  unsigned r = 0x7FFFu + ((u >> 16) & 1u);
  return (unsigned short)((u + r) >> 16);
}

__device__ __forceinline__ void gload16(const unsigned short* g, unsigned short* l) {
  __builtin_amdgcn_global_load_lds(
      (const __attribute__((address_space(1))) unsigned int*)g,
      (__attribute__((address_space(3))) unsigned int*)l, 16, 0, 0);
}

__device__ __forceinline__ f32x4 mfma16(bf16x8 a, bf16x8 b, f32x4 c) {
  return __builtin_amdgcn_mfma_f32_16x16x32_bf16(a, b, c, 0, 0, 0);
}

// ---------------- merged transpose+convert for w1,w3,w2 ----------------
__global__ __launch_bounds__(256) void transpose_all_kernel(
    const float* __restrict__ w1, const float* __restrict__ w3,
    const float* __restrict__ w2,
    unsigned short* __restrict__ W1t, unsigned short* __restrict__ W3t,
    unsigned short* __restrict__ W2t) {
  __shared__ float tile[64][65];
  int z = blockIdx.z;
  int which = z >> 3, e = z & 7;
  const float* src; unsigned short* dst; int M, N;
  if (which == 0)      { src = w1; dst = W1t; M = D_DIM; N = F_DIM; }
  else if (which == 1) { src = w3; dst = W3t; M = D_DIM; N = F_DIM; }
  else                 { src = w2; dst = W2t; M = F_DIM; N = D_DIM; }
  src += (size_t)e * M * N; dst += (size_t)e * M * N;
  int bid = blockIdx.y * gridDim.x + blockIdx.x;
  int nbx = N / 64;
  int i0 = (bid / nbx) * 64, j0 = (bid % nbx) * 64;
  int tid = threadIdx.x;
  int lr = tid >> 4;
  int lc = (tid & 15) * 4;
  #pragma unroll
  for (int p = 0; p < 4; p++) {
    int row = p * 16 + lr;
    float4 v = *(const float4*)&src[(size_t)(i0 + row) * N + j0 + lc];
    tile[row][lc + 0] = v.x; tile[row][lc + 1] = v.y;
    tile[row][lc + 2] = v.z; tile[row][lc + 3] = v.w;
  }
  __syncthreads();
  #pragma unroll
  for (int p = 0; p < 4; p++) {
    int orow = p * 16 + lr;
    unsigned short b0 = f2bf(tile[lc + 0][orow]);
    unsigned short b1 = f2bf(tile[lc + 1][orow]);
    unsigned short b2 = f2bf(tile[lc + 2][orow]);
    unsigned short b3 = f2bf(tile[lc + 3][orow]);
    uint2 o;
    o.x = b0 | ((unsigned)b1 << 16);
    o.y = b2 | ((unsigned)b3 << 16);
    *(uint2*)&dst[(size_t)(j0 + orow) * M + i0 + lc] = o;
  }
}

// ---------------- logits (+ fused x->bf16): 1 wave per token, NO atomics ----------------
__global__ __launch_bounds__(256) void logits_kernel(const float* __restrict__ x,
                                                     const float* __restrict__ gw,
                                                     int* __restrict__ route_e,
                                                     float2* __restrict__ route_w,
                                                     unsigned short* __restrict__ Xb) {
  int lane = threadIdx.x & 63;
  int t = blockIdx.x * 4 + (threadIdx.x >> 6);
  float acc[E_NUM];
  #pragma unroll
  for (int e = 0; e < E_NUM; e++) acc[e] = 0.f;
  const float* xr = x + (size_t)t * D_DIM;
  unsigned short* xbr = Xb + (size_t)t * D_DIM;
  #pragma unroll
  for (int j = 0; j < D_DIM / 64; j++) {
    int d = lane + 64 * j;
    float xv = xr[d];
    xbr[d] = f2bf(xv);
    const float4* g = reinterpret_cast<const float4*>(gw + (size_t)d * E_NUM);
    float4 g0 = g[0], g1 = g[1];
    acc[0] += xv * g0.x; acc[1] += xv * g0.y; acc[2] += xv * g0.z; acc[3] += xv * g0.w;
    acc[4] += xv * g1.x; acc[5] += xv * g1.y; acc[6] += xv * g1.z; acc[7] += xv * g1.w;
  }
  #pragma unroll
  for (int e = 0; e < E_NUM; e++) {
    #pragma unroll
    for (int off = 32; off > 0; off >>= 1) acc[e] += __shfl_xor(acc[e], off);
  }
  if (lane == 0) {
    int e1 = 0; float l1 = acc[0];
    #pragma unroll
    for (int e = 1; e < E_NUM; e++) { if (acc[e] > l1) { l1 = acc[e]; e1 = e; } }
    int e2 = -1; float l2 = -1e30f;
    #pragma unroll
    for (int e = 0; e < E_NUM; e++) { if (e != e1 && acc[e] > l2) { l2 = acc[e]; e2 = e; } }
    float wa = 1.f / (1.f + expf(l2 - l1));
    float wb = 1.f / (1.f + expf(l1 - l2));
    route_e[t] = e1 | (e2 << 8);
    route_w[t] = make_float2(wa, wb);
  }
}

// ---------------- scatter: deterministic prefix-sum compaction + tiles, 1 block ----------
__global__ __launch_bounds__(1024) void scatter_kernel(
    const int* __restrict__ route_e, const float2* __restrict__ route_w,
    int* __restrict__ counts, int4* __restrict__ tiles,
    int* __restrict__ list, float* __restrict__ wts) {
  int tid = threadIdx.x;              // 0..1023, 4 tokens each
  int lane = tid & 63, wv = tid >> 6; // 16 waves
  __shared__ int wave_tot[16][E_NUM];
  __shared__ int wave_base[16][E_NUM];
  __shared__ int tot_s[E_NUM];

  int e_loc[8]; float w_loc[8];
  #pragma unroll
  for (int j = 0; j < 4; j++) {
    int t = tid * 4 + j;
    int re = route_e[t];
    float2 rw = route_w[t];
    e_loc[2 * j]     = re & 0xff; w_loc[2 * j]     = rw.x;
    e_loc[2 * j + 1] = re >> 8;   w_loc[2 * j + 1] = rw.y;
  }
  // per-expert local counts (static indexing only)
  int c[E_NUM], pre[E_NUM];
  #pragma unroll
  for (int e = 0; e < E_NUM; e++) {
    int s = 0;
    #pragma unroll
    for (int j = 0; j < 8; j++) s += (e_loc[j] == e) ? 1 : 0;
    c[e] = s;
  }
  // 64-lane inclusive scan per expert
  #pragma unroll
  for (int e = 0; e < E_NUM; e++) {
    int v = c[e];
    #pragma unroll
    for (int off = 1; off < 64; off <<= 1) {
      int u = __shfl_up(v, off);
      if (lane >= off) v += u;
    }
    pre[e] = v - c[e];
    if (lane == 63) wave_tot[wv][e] = v;
  }
  __syncthreads();
  if (tid < E_NUM) {
    int s = 0;
    for (int w = 0; w < 16; w++) { wave_base[w][tid] = s; s += wave_tot[w][tid]; }
    tot_s[tid] = s;
    counts[tid] = s;
  }
  __syncthreads();
  // write entries at exact positions (token-ordered, deterministic)
  #pragma unroll
  for (int j = 0; j < 8; j++) {
    int e = e_loc[j];
    int off = 0;
    #pragma unroll
    for (int jj = 0; jj < 8; jj++)
      if (jj < j) off += (e_loc[jj] == e) ? 1 : 0;
    int basee = 0, pree = 0;
    #pragma unroll
    for (int ee = 0; ee < E_NUM; ee++)
      if (e == ee) { basee = wave_base[wv][ee]; pree = pre[ee]; }
    int pos = basee + pree + off;
    int t = tid * 4 + (j >> 1);
    list[e * T_TOK + pos] = t * 2 + (j & 1);
    wts[e * T_TOK + pos]  = w_loc[j];
  }
  // tile descriptors (64-row granularity)
  if (tid < MAX_TILES) {
    int4 tt; tt.x = -1; tt.y = 0; tt.z = 0; tt.w = 0;
    int s = 0;
    #pragma unroll
    for (int e = 0; e < E_NUM; e++) {
      int ntl = (tot_s[e] + 63) >> 6;
      if (tid >= s && tid < s + ntl) { tt.x = e; tt.y = (tid - s) * 64; tt.z = tot_s[e]; }
      s += ntl;
    }
    tiles[tid] = tt;
  }
}

// ---------------- GEMM1: H = silu(X@w1)*(X@w3), 64x64 dual tile, 4 waves ----------------
__global__ __launch_bounds__(256, 4) void gemm1_kernel(
    const unsigned short* __restrict__ Xb,   // [T][D] bf16
    const unsigned short* __restrict__ W1t,  // [E][F][D] bf16
    const unsigned short* __restrict__ W3t,  // [E][F][D] bf16
    const int4* __restrict__ tiles, const int* __restrict__ list,
    unsigned short* __restrict__ H) {        // [T*2][F] bf16
  __shared__ unsigned short As[64 * 64];     // 8 KB
  __shared__ unsigned short B1s[64 * 64];    // 8 KB
  __shared__ unsigned short B3s[64 * 64];    // 8 KB
  __shared__ int rid_s[64];

  int4 td = tiles[blockIdx.y];
  int e = td.x;
  if (e < 0) return;
  int base = td.y, cnt = td.z;
  int nt = blockIdx.x;          // 0..31 over F/64
  int tid = threadIdx.x;

  if (tid < 64) {
    int r = base + tid; if (r > cnt - 1) r = cnt - 1;
    rid_s[tid] = list[e * T_TOK + r];
  }
  __syncthreads();

  int lane = tid & 63, wid = tid >> 6;       // wid 0..3
  int sr = lane >> 3;                        // 0..7
  int sg = (lane & 7) ^ sr;                  // pre-swizzled source granule
  const unsigned short* a_src[2];
  #pragma unroll
  for (int t = 0; t < 2; t++)
    a_src[t] = Xb + (size_t)(rid_s[wid * 16 + t * 8 + sr] >> 1) * D_DIM + sg * 8;
  const unsigned short *b1_src[2], *b3_src[2];
  #pragma unroll
  for (int t = 0; t < 2; t++) {
    size_t row = (size_t)e * F_DIM + nt * 64 + wid * 16 + t * 8 + sr;
    b1_src[t] = W1t + row * D_DIM + sg * 8;
    b3_src[t] = W3t + row * D_DIM + sg * 8;
  }

  int wm = (wid >> 1) * 32, wn = (wid & 1) * 32;
  int frow = lane & 15;
  int fk = lane >> 4;

  unsigned offA[2][2], offB[2][2];
  #pragma unroll
  for (int mf = 0; mf < 2; mf++)
    #pragma unroll
    for (int kc = 0; kc < 2; kc++) {
      int m = wm + mf * 16 + frow, gk = kc * 4 + fk;
      offA[mf][kc] = m * 64 + ((gk ^ (m & 7)) * 8);
    }
  #pragma unroll
  for (int nf = 0; nf < 2; nf++)
    #pragma unroll
    for (int kc = 0; kc < 2; kc++) {
      int n = wn + nf * 16 + frow, gk = kc * 4 + fk;
      offB[nf][kc] = n * 64 + ((gk ^ (n & 7)) * 8);
    }

  f32x4 acc1[2][2], acc3[2][2];
  #pragma unroll
  for (int mf = 0; mf < 2; mf++)
    #pragma unroll
    for (int nf = 0; nf < 2; nf++) {
      f32x4 z = {0.f, 0.f, 0.f, 0.f};
      acc1[mf][nf] = z; acc3[mf][nf] = z;
    }

  #pragma unroll 1
  for (int k0 = 0; k0 < D_DIM; k0 += 64) {
    #pragma unroll
    for (int t = 0; t < 2; t++) {
      gload16(a_src[t] + k0, &As[(wid * 16 + t * 8) * 64]);
      gload16(b1_src[t] + k0, &B1s[(wid * 16 + t * 8) * 64]);
      gload16(b3_src[t] + k0, &B3s[(wid * 16 + t * 8) * 64]);
    }
    __syncthreads();
    #pragma unroll
    for (int kc = 0; kc < 2; kc++) {
      bf16x8 a[2], b1[2], b3[2];
      #pragma unroll
      for (int mf = 0; mf < 2; mf++) a[mf] = *(const bf16x8*)&As[offA[mf][kc]];
      #pragma unroll
      for (int nf = 0; nf < 2; nf++) {
        b1[nf] = *(const bf16x8*)&B1s[offB[nf][kc]];
        b3[nf] = *(const bf16x8*)&B3s[offB[nf][kc]];
      }
      #pragma unroll
      for (int mf = 0; mf < 2; mf++)
        #pragma unroll
        for (int nf = 0; nf < 2; nf++) {
          acc1[mf][nf] = mfma16(a[mf], b1[nf], acc1[mf][nf]);
          acc3[mf][nf] = mfma16(a[mf], b3[nf], acc3[mf][nf]);
        }
    }
    __syncthreads();
  }

  #pragma unroll
  for (int mf = 0; mf < 2; mf++) {
    #pragma unroll
    for (int i = 0; i < 4; i++) {
      int m = wm + mf * 16 + fk * 4 + i;
      if (base + m < cnt) {
        int rid = rid_s[m];
        unsigned short* hrow = H + (size_t)rid * F_DIM + nt * 64 + wn;
        #pragma unroll
        for (int nf = 0; nf < 2; nf++) {
          float z = acc1[mf][nf][i];
          float u = acc3[mf][nf][i];
          hrow[nf * 16 + frow] = f2bf((z / (1.f + expf(-z))) * u);
        }
      }
    }
  }
}

// ---------------- GEMM2: out += (H @ w2) * weight, 64x128 tile, 4 waves ------------------
__global__ __launch_bounds__(256, 4) void gemm2_kernel(
    const unsigned short* __restrict__ H,    // [T*2][F] bf16
    const unsigned short* __restrict__ W2t,  // [E][D][F] bf16
    const int4* __restrict__ tiles, const int* __restrict__ list,
    const float* __restrict__ wts,
    float* __restrict__ out) {               // [T][D] fp32 (pre-zeroed)
  __shared__ unsigned short As[64 * 64];     // 8 KB
  __shared__ unsigned short Bs[128 * 64];    // 16 KB
  __shared__ int rid_s[64];
  __shared__ float wt_s[64];

  int4 td = tiles[blockIdx.y];
  int e = td.x;
  if (e < 0) return;
  int base = td.y, cnt = td.z;
  int nt = blockIdx.x;   // 0..7 over D/128
  int tid = threadIdx.x;

  if (tid < 64) {
    int r = base + tid; if (r > cnt - 1) r = cnt - 1;
    rid_s[tid] = list[e * T_TOK + r];
    wt_s[tid] = wts[e * T_TOK + r];
  }
  __syncthreads();

  int lane = tid & 63, wid = tid >> 6;
  int sr = lane >> 3;
  int sg = (lane & 7) ^ sr;
  const unsigned short* a_src[2];
  #pragma unroll
  for (int t = 0; t < 2; t++)
    a_src[t] = H + (size_t)rid_s[wid * 16 + t * 8 + sr] * F_DIM + sg * 8;
  const unsigned short* b_src[4];
  #pragma unroll
  for (int t = 0; t < 4; t++)
    b_src[t] = W2t + ((size_t)e * D_DIM + nt * 128 + wid * 32 + t * 8 + sr) * F_DIM + sg * 8;

  int wm = (wid >> 1) * 32, wn = (wid & 1) * 64;
  int frow = lane & 15;
  int fk = lane >> 4;

  unsigned offA[2][2], offB[4][2];
  #pragma unroll
  for (int mf = 0; mf < 2; mf++)
    #pragma unroll
    for (int kc = 0; kc < 2; kc++) {
      int m = wm + mf * 16 + frow, gk = kc * 4 + fk;
      offA[mf][kc] = m * 64 + ((gk ^ (m & 7)) * 8);
    }
  #pragma unroll
  for (int nf = 0; nf < 4; nf++)
    #pragma unroll
    for (int kc = 0; kc < 2; kc++) {
      int n = wn + nf * 16 + frow, gk = kc * 4 + fk;
      offB[nf][kc] = n * 64 + ((gk ^ (n & 7)) * 8);
    }

  f32x4 acc[2][4];
  #pragma unroll
  for (int mf = 0; mf < 2; mf++)
    #pragma unroll
    for (int nf = 0; nf < 4; nf++) {
      f32x4 z = {0.f, 0.f, 0.f, 0.f};
      acc[mf][nf] = z;
    }

  #pragma unroll 1
  for (int k0 = 0; k0 < F_DIM; k0 += 64) {
    #pragma unroll
    for (int t = 0; t < 2; t++)
      gload16(a_src[t] + k0, &As[(wid * 16 + t * 8) * 64]);
    #pragma unroll
    for (int t = 0; t < 4; t++)
      gload16(b_src[t] + k0, &Bs[(wid * 32 + t * 8) * 64]);
    __syncthreads();
    #pragma unroll
    for (int kc = 0; kc < 2; kc++) {
      bf16x8 a[2], b[4];
      #pragma unroll
      for (int mf = 0; mf < 2; mf++) a[mf] = *(const bf16x8*)&As[offA[mf][kc]];
      #pragma unroll
      for (int nf = 0; nf < 4; nf++) b[nf] = *(const bf16x8*)&Bs[offB[nf][kc]];
      #pragma unroll
      for (int mf = 0; mf < 2; mf++)
        #pragma unroll
        for (int nf = 0; nf < 4; nf++)
          acc[mf][nf] = mfma16(a[mf], b[nf], acc[mf][nf]);
    }
    __syncthreads();
  }

  #pragma unroll
  for (int mf = 0; mf < 2; mf++) {
    #pragma unroll
    for (int i = 0; i < 4; i++) {
      int m = wm + mf * 16 + fk * 4 + i;
      if (base + m < cnt) {
        int tok = rid_s[m] >> 1;
        float w = wt_s[m];
        float* orow = out + (size_t)tok * D_DIM + nt * 128 + wn;
        #pragma unroll
        for (int nf = 0; nf < 4; nf++)
          atomicAdd(&orow[nf * 16 + frow], acc[mf][nf][i] * w);
      }
    }
  }
}

extern "C" void kernel_launch(void* const* d_in, const int* in_sizes, int n_in,
                              void* d_out, int out_size, void* d_ws, size_t ws_size,
                              hipStream_t stream) {
  const float* x  = (const float*)d_in[0];
  const float* gw = (const float*)d_in[1];
  const float* w1 = (const float*)d_in[2];
  const float* w2 = (const float*)d_in[3];
  const float* w3 = (const float*)d_in[4];
  float* out = (float*)d_out;

  char* ws = (char*)d_ws;
  const size_t LISTB = (size_t)E_NUM * T_TOK * 4;
  size_t o_counts  = 0;
  size_t o_tiles   = 256;                                   // int4[136] = 2176 B
  size_t o_route_e = 4096;                                  // int[T] = 16 KB
  size_t o_route_w = o_route_e + (size_t)T_TOK * 4;         // float2[T] = 32 KB
  size_t o_list    = o_route_w + (size_t)T_TOK * 8;
  size_t o_wts     = o_list + LISTB;
  size_t o_Xb      = o_wts + LISTB;
  size_t o_W1t     = o_Xb + (size_t)T_TOK * D_DIM * 2;
  size_t wt_sz     = (size_t)E_NUM * F_DIM * D_DIM * 2;
  size_t o_W3t     = o_W1t + wt_sz;
  size_t o_W2t     = o_W3t + wt_sz;
  size_t o_H       = o_W2t + wt_sz;

  int* counts   = (int*)(ws + o_counts);
  int4* tiles   = (int4*)(ws + o_tiles);
  int* route_e  = (int*)(ws + o_route_e);
  float2* route_w = (float2*)(ws + o_route_w);
  int* list     = (int*)(ws + o_list);
  float* wts    = (float*)(ws + o_wts);
  unsigned short* Xb  = (unsigned short*)(ws + o_Xb);
  unsigned short* W1t = (unsigned short*)(ws + o_W1t);
  unsigned short* W3t = (unsigned short*)(ws + o_W3t);
  unsigned short* W2t = (unsigned short*)(ws + o_W2t);
  unsigned short* H   = (unsigned short*)(ws + o_H);

  hipMemsetAsync(out, 0, (size_t)out_size * 4, stream);

  transpose_all_kernel<<<dim3(32, 16, 24), 256, 0, stream>>>(
      w1, w3, w2, W1t, W3t, W2t);

  logits_kernel<<<dim3(T_TOK / 4), 256, 0, stream>>>(x, gw, route_e, route_w, Xb);
  scatter_kernel<<<dim3(1), 1024, 0, stream>>>(route_e, route_w, counts, tiles, list, wts);

  gemm1_kernel<<<dim3(F_DIM / 64, MAX_TILES), 256, 0, stream>>>(
      Xb, W1t, W3t, tiles, list, H);
  gemm2_kernel<<<dim3(D_DIM / 128, MAX_TILES), 256, 0, stream>>>(
      H, W2t, tiles, list, wts, out);
}